// Round 13
// baseline (564.879 us; speedup 1.0000x reference)
//
#include <hip/hip_runtime.h>
#include <math.h>

#define NHEADS   64
#define EMB      2048
#define STATE    128
#define KCONV    4
#define HEAD_DIM 64
#define CHUNK    128
#define SEQL     2048
#define NBATCH   2
#define NCH      (SEQL/CHUNK)          // 16
#define INTER    (NHEADS*HEAD_DIM)     // 4096
#define CONVD    (INTER + 2*STATE)     // 4352
#define PROJD    (INTER + CONVD + NHEADS) // 8512
#define ROWS     (NBATCH*SEQL)         // 4096
#define EPSV     1e-6f

__device__ __forceinline__ float sigmoidf_(float x){ return 1.f/(1.f+__expf(-x)); }

__device__ __forceinline__ float b2f(ushort u){
  union{float f; unsigned u;} x; x.u = ((unsigned)u)<<16; return x.f;
}
__device__ __forceinline__ ushort f2b(float f){
  union{float f; unsigned u;} x; x.f=f;
  unsigned r = x.u + 0x7FFFu + ((x.u>>16)&1u);
  return (ushort)(r>>16);
}
__device__ __forceinline__ float4 ld4(const float* p){ return *(const float4*)p; }
__device__ __forceinline__ float4 ld4(const ushort* p){
  ushort4 v = *(const ushort4*)p;
  return make_float4(b2f(v.x),b2f(v.y),b2f(v.z),b2f(v.w));
}
__device__ __forceinline__ void st4(float* p, float4 v){ *(float4*)p = v; }
__device__ __forceinline__ void st4(ushort* p, float4 v){
  ushort4 o; o.x=f2b(v.x); o.y=f2b(v.y); o.z=f2b(v.z); o.w=f2b(v.w);
  *(ushort4*)p = o;
}
__device__ __forceinline__ void stc(float* p, float v){ *p = v; }
__device__ __forceinline__ void stc(ushort* p, float v){ *p = f2b(v); }

typedef __attribute__((ext_vector_type(8))) short short8v;   // 8 bf16 = 4 VGPR
typedef __attribute__((ext_vector_type(4))) float float4v;

// vector store of one acc frag (4 consecutive elems on the reg axis)
__device__ __forceinline__ void stv4(float* p, float4v v){
  *(float4*)p = make_float4(v[0],v[1],v[2],v[3]);
}
__device__ __forceinline__ void stv4(ushort* p, float4v v){
  ushort4 o; o.x=f2b(v[0]); o.y=f2b(v[1]); o.z=f2b(v[2]); o.w=f2b(v[3]);
  *(ushort4*)p = o;
}

// merged x+Wi f32->bf16 convert (both sizes multiples of 8)
__global__ __launch_bounds__(256) void conv2_bf16_kernel(
    const float* __restrict__ a, ushort* __restrict__ oa, long na,
    const float* __restrict__ b, ushort* __restrict__ ob, long nb)
{
  long i = ((long)blockIdx.x*256 + threadIdx.x) * 8;
  if (i < na) {
    st4(oa + i, *(const float4*)(a + i));
    st4(oa + i + 4, *(const float4*)(a + i + 4));
  } else {
    long j = i - na;
    if (j < nb) {
      st4(ob + j, *(const float4*)(b + j));
      st4(ob + j + 4, *(const float4*)(b + j + 4));
    }
  }
}

__global__ __launch_bounds__(256) void f32_to_bf16_kernel(
    const float* __restrict__ in, ushort* __restrict__ out, long n)
{
  long i = ((long)blockIdx.x*256 + threadIdx.x) * 8;
  if (i >= n) return;
  st4(out + i, *(const float4*)(in + i));
  st4(out + i + 4, *(const float4*)(in + i + 4));
}

#define GLL16(g, l) __builtin_amdgcn_global_load_lds( \
    (const __attribute__((address_space(1))) void*)(g), \
    (__attribute__((address_space(3))) void*)(l), 16, 0, 0)

// ---------------------------------------------------------------------------
// MFMA bf16 NT GEMM (m97 structure, BK=64, R10/R12-verified epilogue).
// Conflict-free LDS swizzle. XCD-aware tile swizzle.
// M % 128 == 0; N guarded; K % 64 == 0.
// ---------------------------------------------------------------------------
template<typename TC>
__global__ __launch_bounds__(256) void gemm_mfma_bt(
    const ushort* __restrict__ A, int lda,
    const ushort* __restrict__ B, int ldb,
    TC* __restrict__ C, int ldc,
    int N, int K)
{
  __shared__ ushort As[2][128*32];
  __shared__ ushort Bs[2][128*32];
  const int t = threadIdx.x;
  const int lt = t & 63, w = t >> 6;
  const int wr = w >> 1, wc = w & 1;

  const int nwg = gridDim.x * gridDim.y;
  int orig = blockIdx.x + gridDim.x * blockIdx.y;
  int tile = orig;
  if ((nwg & 7) == 0) tile = (orig & 7) * (nwg >> 3) + (orig >> 3);
  const int m0 = (tile / gridDim.x) * 128;
  const int n0 = (tile % gridDim.x) * 128;

  float4v acc[4][4];
  #pragma unroll
  for (int i=0;i<4;++i)
    #pragma unroll
    for (int j=0;j<4;++j) acc[i][j] = float4v{0.f,0.f,0.f,0.f};

  const int srow = t >> 2;
  const int scol = ((t & 3) ^ ((srow >> 1) & 3)) * 8;   // source-side swizzle
  const int bn0 = min(n0 + srow, N-1);
  const int bn1 = min(n0 + 64 + srow, N-1);
  const long aoff0 = (long)(m0 + srow) * lda + scol;
  const long aoff1 = (long)(m0 + 64 + srow) * lda + scol;
  const long boff0 = (long)bn0 * ldb + scol;
  const long boff1 = (long)bn1 * ldb + scol;
  const int lr = lt & 15, lks = lt >> 4;

  for (int k0 = 0; k0 < K; k0 += 64) {
    GLL16(A + aoff0 + k0,      As[0] + t*8);
    GLL16(A + aoff1 + k0,      As[0] + 2048 + t*8);
    GLL16(B + boff0 + k0,      Bs[0] + t*8);
    GLL16(B + boff1 + k0,      Bs[0] + 2048 + t*8);
    GLL16(A + aoff0 + k0 + 32, As[1] + t*8);
    GLL16(A + aoff1 + k0 + 32, As[1] + 2048 + t*8);
    GLL16(B + boff0 + k0 + 32, Bs[1] + t*8);
    GLL16(B + boff1 + k0 + 32, Bs[1] + 2048 + t*8);
    __syncthreads();
    #pragma unroll
    for (int hB = 0; hB < 2; ++hB) {
      short8v af[4], bf[4];
      #pragma unroll
      for (int i = 0; i < 4; ++i) {
        int ra = wr*64 + i*16 + lr;
        af[i] = *(const short8v*)(As[hB] + ra*32 + ((lks ^ ((ra>>1)&3)) << 3));
        int rb = wc*64 + i*16 + lr;
        bf[i] = *(const short8v*)(Bs[hB] + rb*32 + ((lks ^ ((rb>>1)&3)) << 3));
      }
      #pragma unroll
      for (int i = 0; i < 4; ++i)
        #pragma unroll
        for (int j = 0; j < 4; ++j)
          acc[i][j] = __builtin_amdgcn_mfma_f32_16x16x32_bf16(af[i], bf[j], acc[i][j], 0, 0, 0);
    }
    __syncthreads();
  }

  const int cr = (lt >> 4) * 4;   // C/D: col=lane&15, row=(lane>>4)*4+reg (m89)
  const int cc = lt & 15;
  #pragma unroll
  for (int i = 0; i < 4; ++i) {
    #pragma unroll
    for (int j = 0; j < 4; ++j) {
      int col = n0 + wc*64 + j*16 + cc;
      if (col < N) {
        #pragma unroll
        for (int r = 0; r < 4; ++r) {
          int row = m0 + wr*64 + i*16 + cr + r;
          stc(C + (long)row*ldc + col, acc[i][j][r]);
        }
      }
    }
  }
}

// ---------------------------------------------------------------------------
// MFMA G kernel, 4-way row split (128 blocks): block = (bc, row-quarter q).
// Swapped-operand epilogue with float4 stores (R11-verified mapping).
// ---------------------------------------------------------------------------
__global__ __launch_bounds__(256) void g_mfma_kernel(
    const ushort* __restrict__ conv, float* __restrict__ G)
{
  const int bc = blockIdx.x >> 2, q = blockIdx.x & 3;
  const long r0 = (long)bc*CHUNK;
  __shared__ ushort Cs[32][136];
  __shared__ ushort Bs[128][136];
  const int t = threadIdx.x;
  const int lt = t & 63, w = t >> 6;
  const int lr = lt & 15, lk = (lt >> 4) * 8;

  for (int i = t; i < 32*16; i += 256) {
    int r = i >> 4, n0 = (i & 15) * 8;
    *(short8v*)&Cs[r][n0] = *(const short8v*)(conv + (r0+q*32+r)*CONVD + INTER + STATE + n0);
  }
  for (int i = t; i < 128*16; i += 256) {
    int r = i >> 4, n0 = (i & 15) * 8;
    *(short8v*)&Bs[r][n0] = *(const short8v*)(conv + (r0+r)*CONVD + INTER + n0);
  }
  __syncthreads();

  // wave w: m-frag mi = w>>1 (16 rows), n-half nh = (w&1)*4 (4 of 8 s-frags)
  const int mi = w >> 1, nh = (w & 1) * 4;
  float4v acc[4];
  #pragma unroll
  for (int j=0;j<4;++j) acc[j] = float4v{0,0,0,0};
  #pragma unroll
  for (int kk = 0; kk < 4; ++kk) {
    short8v a0 = *(const short8v*)&Cs[mi*16 + lr][kk*32 + lk];
    #pragma unroll
    for (int nj = 0; nj < 4; ++nj) {
      short8v bv = *(const short8v*)&Bs[(nh+nj)*16 + lr][kk*32 + lk];
      acc[nj] = __builtin_amdgcn_mfma_f32_16x16x32_bf16(bv, a0, acc[nj], 0, 0, 0);
    }
  }
  float* Gb = G + (long)bc*CHUNK*CHUNK;
  const int cl = lt & 15, cs4 = (lt >> 4) * 4;
  const int l = q*32 + mi*16 + cl;
  #pragma unroll
  for (int nj = 0; nj < 4; ++nj)
    stv4(Gb + l*CHUNK + (nh+nj)*16 + cs4, acc[nj]);
}

// ---------------------------------------------------------------------------
// Depthwise causal conv (K=4) + bias + SiLU — 8-wide (16B loads/stores)
// ---------------------------------------------------------------------------
__global__ __launch_bounds__(256) void conv_silu_kernel(
    const ushort* __restrict__ proj, const float* __restrict__ cw,
    const float* __restrict__ cb, ushort* __restrict__ out)
{
  const int C8 = CONVD/8;                 // 544
  long idx = (long)blockIdx.x*256 + threadIdx.x;
  if (idx >= (long)ROWS*C8) return;
  int r = (int)(idx / C8);
  int c = (int)(idx % C8) * 8;
  int tt = r & (SEQL-1);
  float acc[8];
  {
    float4 b0 = *(const float4*)(cb + c);
    float4 b1 = *(const float4*)(cb + c + 4);
    acc[0]=b0.x; acc[1]=b0.y; acc[2]=b0.z; acc[3]=b0.w;
    acc[4]=b1.x; acc[5]=b1.y; acc[6]=b1.z; acc[7]=b1.w;
  }
  float wj[8][4];
  #pragma unroll
  for (int e = 0; e < 8; ++e) {
    float4 wv = *(const float4*)(cw + (c+e)*KCONV);
    wj[e][0]=wv.x; wj[e][1]=wv.y; wj[e][2]=wv.z; wj[e][3]=wv.w;
  }
  #pragma unroll
  for (int j = 0; j < KCONV; ++j) {
    int tr = tt - (KCONV-1) + j;
    if (tr >= 0) {
      short8v v = *(const short8v*)(proj + (long)(r - (KCONV-1) + j)*PROJD + INTER + c);
      #pragma unroll
      for (int e = 0; e < 8; ++e)
        acc[e] = fmaf(b2f((ushort)v[e]), wj[e][j], acc[e]);
    }
  }
  short8v o;
  #pragma unroll
  for (int e = 0; e < 8; ++e) {
    float v = acc[e] * sigmoidf_(acc[e]);
    o[e] = (short)f2b(v);
  }
  *(short8v*)(out + (long)r*CONVD + c) = o;
}

// ---------------------------------------------------------------------------
// Fused dt (softplus) + per-chunk cumsum of A*dt (R8-verified)
// ---------------------------------------------------------------------------
__global__ __launch_bounds__(256) void dt_acum_kernel(
    const ushort* __restrict__ proj, const float* __restrict__ dt_bias,
    const float* __restrict__ A_log, float* __restrict__ dtb,
    float* __restrict__ acum)
{
  const int bc = blockIdx.x;
  const long r0 = (long)bc*CHUNK;
  __shared__ float dts[CHUNK][NHEADS+1];
  const int t = threadIdx.x;
  for (int i = t; i < CHUNK*8; i += 256) {
    int l = i >> 3, h0 = (i & 7) * 8;
    short8v v = *(const short8v*)(proj + (r0+l)*PROJD + INTER + CONVD + h0);
    #pragma unroll
    for (int j = 0; j < 8; ++j) {
      float xv = b2f((ushort)v[j]) + dt_bias[h0+j];
      float sp = fmaxf(xv, 0.f) + __logf(1.f + __expf(-fabsf(xv)));
      dts[l][h0+j] = sp;
      dtb[(r0+l)*NHEADS + h0 + j] = sp;
    }
  }
  __syncthreads();
  if (t < NHEADS) {
    float Ah = -__expf(A_log[t]);
    float acc = 0.f;
    float* o = acum + ((long)bc*NHEADS + t)*CHUNK;
    for (int l = 0; l < CHUNK; ++l) { acc = fmaf(Ah, dts[l][t], acc); o[l] = acc; }
  }
}

// ---------------------------------------------------------------------------
// MFMA states kernel (R11-verified, swapped-operand epilogue, 8B stores)
// ---------------------------------------------------------------------------
__global__ __launch_bounds__(256) void states_mfma_kernel(
    const ushort* __restrict__ conv, const float* __restrict__ dtb,
    const float* __restrict__ acum, ushort* __restrict__ states)
{
  const int h = blockIdx.x, c = blockIdx.y, b = blockIdx.z;
  const int bc = b*NCH + c;
  const long r0 = (long)bc*CHUNK;
  __shared__ ushort Ahi[64][136];
  __shared__ ushort Alo[64][136];
  __shared__ ushort Bt[128][136];
  __shared__ float arow[CHUNK];
  __shared__ float wrow[CHUNK];
  const int t = threadIdx.x;
  const int lt = t & 63, w = t >> 6;
  const int lr = lt & 15, lk = (lt >> 4) * 8;

  if (t < CHUNK) arow[t] = acum[((long)bc*NHEADS + h)*CHUNK + t];
  __syncthreads();
  if (t < CHUNK) wrow[t] = dtb[(r0 + t)*NHEADS + h] * __expf(arow[CHUNK-1] - arow[t]);
  __syncthreads();

  for (int i = t; i < CHUNK*HEAD_DIM/8; i += 256) {
    int l = i >> 3, p0 = (i & 7) * 8;
    short8v v = *(const short8v*)(conv + (r0+l)*CONVD + h*HEAD_DIM + p0);
    float wl = wrow[l];
    #pragma unroll
    for (int j = 0; j < 8; ++j) {
      float f = b2f((ushort)v[j]) * wl;
      ushort hb = f2b(f);
      Ahi[p0+j][l] = hb;
      Alo[p0+j][l] = f2b(f - b2f(hb));
    }
  }
  for (int i = t; i < CHUNK*STATE/8; i += 256) {
    int l = i >> 4, n0 = (i & 15) * 8;
    short8v v = *(const short8v*)(conv + (r0+l)*CONVD + INTER + n0);
    #pragma unroll
    for (int j = 0; j < 8; ++j) Bt[n0+j][l] = (ushort)v[j];
  }
  __syncthreads();

  float4v acc[8];
  #pragma unroll
  for (int j = 0; j < 8; ++j) acc[j] = float4v{0,0,0,0};
  #pragma unroll
  for (int kk = 0; kk < 4; ++kk) {
    short8v ahi = *(const short8v*)&Ahi[w*16 + lr][kk*32 + lk];
    short8v alo = *(const short8v*)&Alo[w*16 + lr][kk*32 + lk];
    #pragma unroll
    for (int nj = 0; nj < 8; ++nj) {
      short8v bv = *(const short8v*)&Bt[nj*16 + lr][kk*32 + lk];
      acc[nj] = __builtin_amdgcn_mfma_f32_16x16x32_bf16(bv, ahi, acc[nj], 0, 0, 0);
      acc[nj] = __builtin_amdgcn_mfma_f32_16x16x32_bf16(bv, alo, acc[nj], 0, 0, 0);
    }
  }
  ushort* so = states + ((long)bc*NHEADS + h)*HEAD_DIM*STATE;
  const int cp = lt & 15, cn4 = (lt >> 4) * 4;
  const int p = w*16 + cp;
  #pragma unroll
  for (int nj = 0; nj < 8; ++nj)
    stv4(so + p*STATE + nj*16 + cn4, acc[nj]);
}

// in-place inter-chunk scan — 8-way p-split (1024 blocks, 4 regs/thread)
__global__ __launch_bounds__(256) void scan_kernel(
    ushort* __restrict__ states, const float* __restrict__ acum)
{
  const int blk = blockIdx.x;
  const int bh = blk >> 3, pq = blk & 7;
  const int b = bh >> 6, h = bh & 63;
  const int t = threadIdx.x;
  const int base = pq * 8 * STATE;     // 8 p-rows per eighth (1024 elems)
  float acc[4];
  #pragma unroll
  for (int i=0;i<4;++i) acc[i]=0.f;
  for (int c = 0; c < NCH; ++c) {
    const long bch = ((long)(b*NCH + c)*NHEADS + h);
    float lam = __expf(acum[bch*CHUNK + CHUNK-1]);
    ushort* sb = states + bch*HEAD_DIM*STATE + base;
    #pragma unroll
    for (int i = 0; i < 4; ++i) {
      float v = b2f(sb[t + i*256]);
      sb[t + i*256] = f2b(acc[i]);
      acc[i] = fmaf(acc[i], lam, v);
    }
  }
}

// ---------------------------------------------------------------------------
// MFMA y-kernel (R11/R12-verified: fused chunk-halves, swapped epilogue,
// mh=0 zero-K skip, vectorized C-staging).
// ---------------------------------------------------------------------------
__global__ __launch_bounds__(256) void y_mfma_kernel(
    const ushort* __restrict__ conv, const float* __restrict__ dtb,
    const float* __restrict__ acum, const float* __restrict__ G,
    const ushort* __restrict__ states, const float* __restrict__ Dp,
    ushort* __restrict__ proj)
{
  const int h = blockIdx.x, c = blockIdx.y, b = blockIdx.z;
  const int bc = b*NCH + c;
  const long r0 = (long)bc*CHUNK;

  __shared__ float  Af[64][132];     // W (f32), then C; per-mh
  __shared__ ushort B0[64][136];     // hid^T: B0[p][s], full chunk
  __shared__ ushort B1[64][136];     // init:  B1[p][n]
  __shared__ float arow[CHUNK];
  __shared__ float dtr[CHUNK];
  __shared__ float el[CHUNK];

  const int t = threadIdx.x;
  const int lt = t & 63, w = t >> 6;
  const int lr = lt & 15, lk = (lt >> 4) * 8;

  if (t < CHUNK) {
    arow[t] = acum[((long)bc*NHEADS + h)*CHUNK + t];
    dtr[t]  = dtb[(r0 + t)*NHEADS + h];
  }
  __syncthreads();

  if (t < CHUNK) el[t] = __expf(arow[t]);
  // B0 = hid^T (full chunk)
  for (int i = t; i < CHUNK*HEAD_DIM/8; i += 256) {
    int s = i >> 3, p0 = (i & 7) * 8;
    short8v v = *(const short8v*)(conv + (r0+s)*CONVD + h*HEAD_DIM + p0);
    #pragma unroll
    for (int j = 0; j < 8; ++j) B0[p0+j][s] = (ushort)v[j];
  }
  // B1 = init states
  {
    const ushort* stb = states + ((long)bc*NHEADS + h)*HEAD_DIM*STATE;
    for (int i = t; i < HEAD_DIM*STATE/8; i += 256) {
      int p = i >> 4, n0 = (i & 15) * 8;
      *(short8v*)&B1[p][n0] = *(const short8v*)(stb + p*STATE + n0);
    }
  }
  // Af = W(mh=0): rows 0..63, cols 0..63 only (s<=l<64)
  {
    const float* Gb = G + (long)bc*CHUNK*CHUNK;
    for (int i = t; i < 64*64; i += 256) {
      int ll = i >> 6, s = i & 63;
      float wv = 0.f;
      if (s <= ll) wv = Gb[ll*CHUNK + s] * __expf(arow[ll] - arow[s]) * dtr[s];
      Af[ll][s] = wv;
    }
  }
  __syncthreads();

  const float Dh = Dp[h];
  const int cl = lt & 15, cp4 = (lt >> 4) * 4;

  #pragma unroll
  for (int mh = 0; mh < 2; ++mh) {
    const int mbase = mh * 64;
    if (mh == 1) {
      __syncthreads();     // mm2(0) readers of Af done
      const float* Gb = G + (long)bc*CHUNK*CHUNK;
      for (int i = t; i < 64*CHUNK; i += 256) {
        int ll = i >> 7, s = i & 127;
        int l = 64 + ll;
        float wv = 0.f;
        if (s <= l) wv = Gb[l*CHUNK + s] * __expf(arow[l] - arow[s]) * dtr[s];
        Af[ll][s] = wv;
      }
      __syncthreads();
    }

    float4v acc1[4], acc2[4];
    #pragma unroll
    for (int j = 0; j < 4; ++j) { acc1[j] = float4v{0,0,0,0}; acc2[j] = float4v{0,0,0,0}; }

    // mm1: Y_diag, W split hi/lo (mh=0: only K columns 0..63 nonzero)
    const int kkmax = mh ? 4 : 2;
    for (int kk = 0; kk < kkmax; ++kk) {
      const float* ap = &Af[w*16 + lr][kk*32 + lk];
      float a8[8];
      *(float4*)&a8[0] = *(const float4*)ap;
      *(float4*)&a8[4] = *(const float4*)(ap + 4);
      short8v ahi, alo;
      #pragma unroll
      for (int e = 0; e < 8; ++e) {
        ushort hb = f2b(a8[e]);
        float rem = a8[e] - b2f(hb);
        ahi[e] = (short)hb;
        alo[e] = (short)f2b(rem);
      }
      #pragma unroll
      for (int nj = 0; nj < 4; ++nj) {
        short8v bfv = *(const short8v*)&B0[nj*16 + lr][kk*32 + lk];
        acc1[nj] = __builtin_amdgcn_mfma_f32_16x16x32_bf16(bfv, ahi, acc1[nj], 0, 0, 0);
        acc1[nj] = __builtin_amdgcn_mfma_f32_16x16x32_bf16(bfv, alo, acc1[nj], 0, 0, 0);
      }
    }
    __syncthreads();

    // Af = C rows of this half (exact bf16 values, staged f32) — vectorized
    for (int i = t; i < 64*STATE/8; i += 256) {
      int ll = i >> 4, n0 = (i & 15) * 8;
      short8v v = *(const short8v*)(conv + (r0 + mbase + ll)*CONVD + INTER + STATE + n0);
      #pragma unroll
      for (int j = 0; j < 8; ++j) Af[ll][n0+j] = b2f((ushort)v[j]);
    }
    __syncthreads();

    // mm2: C @ init^T (exact)
    #pragma unroll
    for (int kk = 0; kk < 4; ++kk) {
      const float* ap = &Af[w*16 + lr][kk*32 + lk];
      float a8[8];
      *(float4*)&a8[0] = *(const float4*)ap;
      *(float4*)&a8[4] = *(const float4*)(ap + 4);
      short8v ahi;
      #pragma unroll
      for (int e = 0; e < 8; ++e) ahi[e] = (short)f2b(a8[e]);
      #pragma unroll
      for (int nj = 0; nj < 4; ++nj) {
        short8v bfv = *(const short8v*)&B1[nj*16 + lr][kk*32 + lk];
        acc2[nj] = __builtin_amdgcn_mfma_f32_16x16x32_bf16(bfv, ahi, acc2[nj], 0, 0, 0);
      }
    }

    // epilogue: swapped mapping -> lane owns l = w*16+cl, 4 consecutive p
    const int ll = w*16 + cl;
    const float elv = el[mbase + ll];
    #pragma unroll
    for (int nj = 0; nj < 4; ++nj) {
      int p0 = nj*16 + cp4;
      float4v yv;
      #pragma unroll
      for (int r = 0; r < 4; ++r) {
        float hid_raw = b2f(B0[p0 + r][mbase + ll]);
        yv[r] = acc1[nj][r] + elv*acc2[nj][r] + Dh*hid_raw;
      }
      stv4(proj + (r0 + mbase + ll)*PROJD + INTER + h*HEAD_DIM + p0, yv);
    }
  }
}

// yg = y*silu(gate); rmsnorm — 16B loads/stores
__global__ __launch_bounds__(256) void gate_norm_kernel(
    ushort* __restrict__ proj, const float* __restrict__ nw)
{
  const int r = blockIdx.x;
  const int t = threadIdx.x;
  __shared__ float red[256];
  ushort* gate = proj + (long)r*PROJD;
  ushort* y = gate + INTER;
  float vals[16];
  float ss = 0.f;
  #pragma unroll
  for (int k = 0; k < 2; ++k) {
    int j = (t + k*256) * 8;
    short8v g8 = *(const short8v*)(gate + j);
    short8v y8 = *(const short8v*)(y + j);
    #pragma unroll
    for (int e = 0; e < 8; ++e) {
      float gv = b2f((ushort)g8[e]);
      float yv = b2f((ushort)y8[e]);
      float v = yv * gv * sigmoidf_(gv);
      vals[k*8+e] = v;
      ss += v*v;
    }
  }
  red[t] = ss;
  __syncthreads();
  for (int sft = 128; sft > 0; sft >>= 1) {
    if (t < sft) red[t] += red[t+sft];
    __syncthreads();
  }
  float scale = rsqrtf(red[0] / (float)INTER + EPSV);
  #pragma unroll
  for (int k = 0; k < 2; ++k) {
    int j = (t + k*256) * 8;
    short8v o;
    #pragma unroll
    for (int e = 0; e < 8; ++e)
      o[e] = (short)f2b(vals[k*8+e] * scale * nw[j+e]);
    *(short8v*)(y + j) = o;
  }
}

extern "C" void kernel_launch(void* const* d_in, const int* in_sizes, int n_in,
                              void* d_out, int out_size, void* d_ws, size_t ws_size,
                              hipStream_t stream) {
  const float* x       = (const float*)d_in[0];
  const float* Wi      = (const float*)d_in[1];
  const float* cw      = (const float*)d_in[2];
  const float* cb      = (const float*)d_in[3];
  const float* dt_bias = (const float*)d_in[4];
  const float* A_log   = (const float*)d_in[5];
  const float* Dp      = (const float*)d_in[6];
  const float* nw      = (const float*)d_in[7];
  const float* Wo      = (const float*)d_in[8];
  float* out = (float*)d_out;

  ushort* projb = (ushort*)d_ws;
  ushort* R     = projb + (size_t)ROWS*PROJD;
  ushort* xb    = R;
  ushort* Wib   = R + (size_t)ROWS*EMB;
  ushort* Wob   = R;
  ushort* convb = R;
  float*  dtb   = (float*)(convb + (size_t)ROWS*CONVD);
  float*  acum  = dtb  + (size_t)ROWS*NHEADS;
  float*  Gb    = acum + (size_t)NBATCH*NCH*NHEADS*CHUNK;
  ushort* st    = (ushort*)(Gb + (size_t)NBATCH*NCH*CHUNK*CHUNK);

  size_t need = (size_t)ROWS*PROJD*2 + (size_t)ROWS*CONVD*2
              + (size_t)ROWS*NHEADS*4 + (size_t)NBATCH*NCH*NHEADS*CHUNK*4
              + (size_t)NBATCH*NCH*CHUNK*CHUNK*4
              + (size_t)NBATCH*NCH*NHEADS*HEAD_DIM*STATE*2;
  if (ws_size < need) return;

  // 0. convert x + Wi to bf16 (single launch)
  {
    long na = (long)ROWS*EMB, nb = (long)PROJD*EMB;
    conv2_bf16_kernel<<<(int)((na+nb)/8/256), 256, 0, stream>>>(x, xb, na, Wi, Wib, nb);
  }
  // 1. proj = x @ Wi^T  (MFMA BK=64) -> bf16; grid 67x32
  gemm_mfma_bt<ushort><<<dim3((PROJD+127)/128, ROWS/128), 256, 0, stream>>>(
      xb, EMB, Wib, EMB, projb, PROJD, PROJD, EMB);
  // 2. causal depthwise conv + silu -> bf16 (8-wide)
  conv_silu_kernel<<<(int)(((long)ROWS*(CONVD/8)+255)/256), 256, 0, stream>>>(
      projb, cw, cb, convb);
  // 3. fused dt softplus + chunk cumsum of A*dt
  dt_acum_kernel<<<NBATCH*NCH, 256, 0, stream>>>(projb, dt_bias, A_log, dtb, acum);
  // 4. G = C B^T per (b,chunk)  (MFMA, 4-way row split: 128 blocks)
  g_mfma_kernel<<<NBATCH*NCH*4, 256, 0, stream>>>(convb, Gb);
  // 5. per-chunk end states -> bf16 (MFMA)
  states_mfma_kernel<<<dim3(NHEADS, NCH, NBATCH), 256, 0, stream>>>(convb, dtb, acum, st);
  // 6. sequential inter-chunk scan (in place, 8-way p-split: 1024 blocks)
  scan_kernel<<<NBATCH*NHEADS*8, 256, 0, stream>>>(st, acum);
  // 7. y = Y_diag + Y_off + D*hid  (MFMA, both halves fused; 1024 blocks)
  y_mfma_kernel<<<dim3(NHEADS, NCH, NBATCH), 256, 0, stream>>>(
      convb, dtb, acum, Gb, st, Dp, projb);
  // 8. gating + RMSNorm (in place, bf16, 16B vec)
  gate_norm_kernel<<<ROWS, 256, 0, stream>>>(projb, nw);
  // 8.5 convert Wo to bf16
  f32_to_bf16_kernel<<<(int)((long)EMB*INTER/8/256), 256, 0, stream>>>(Wo, Wob, (long)EMB*INTER);
  // 9. out = yn @ Wo^T  (MFMA BK=64) -> f32; 16x32
  gemm_mfma_bt<float><<<dim3(EMB/128, ROWS/128), 256, 0, stream>>>(
      projb + INTER, PROJD, Wob, INTER, out, EMB, EMB, INTER);
}

// Round 14
// 554.725 us; speedup vs baseline: 1.0183x; 1.0183x over previous
//
#include <hip/hip_runtime.h>
#include <math.h>

#define NHEADS   64
#define EMB      2048
#define STATE    128
#define KCONV    4
#define HEAD_DIM 64
#define CHUNK    128
#define SEQL     2048
#define NBATCH   2
#define NCH      (SEQL/CHUNK)          // 16
#define INTER    (NHEADS*HEAD_DIM)     // 4096
#define CONVD    (INTER + 2*STATE)     // 4352
#define PROJD    (INTER + CONVD + NHEADS) // 8512
#define ROWS     (NBATCH*SEQL)         // 4096
#define EPSV     1e-6f

__device__ __forceinline__ float sigmoidf_(float x){ return 1.f/(1.f+__expf(-x)); }

__device__ __forceinline__ float b2f(ushort u){
  union{float f; unsigned u;} x; x.u = ((unsigned)u)<<16; return x.f;
}
__device__ __forceinline__ ushort f2b(float f){
  union{float f; unsigned u;} x; x.f=f;
  unsigned r = x.u + 0x7FFFu + ((x.u>>16)&1u);
  return (ushort)(r>>16);
}
__device__ __forceinline__ float4 ld4(const float* p){ return *(const float4*)p; }
__device__ __forceinline__ float4 ld4(const ushort* p){
  ushort4 v = *(const ushort4*)p;
  return make_float4(b2f(v.x),b2f(v.y),b2f(v.z),b2f(v.w));
}
__device__ __forceinline__ void st4(float* p, float4 v){ *(float4*)p = v; }
__device__ __forceinline__ void st4(ushort* p, float4 v){
  ushort4 o; o.x=f2b(v.x); o.y=f2b(v.y); o.z=f2b(v.z); o.w=f2b(v.w);
  *(ushort4*)p = o;
}
__device__ __forceinline__ void stc(float* p, float v){ *p = v; }
__device__ __forceinline__ void stc(ushort* p, float v){ *p = f2b(v); }

typedef __attribute__((ext_vector_type(8))) short short8v;   // 8 bf16 = 4 VGPR
typedef __attribute__((ext_vector_type(4))) float float4v;

// vector store of one acc frag (4 consecutive elems on the reg axis)
__device__ __forceinline__ void stv4(float* p, float4v v){
  *(float4*)p = make_float4(v[0],v[1],v[2],v[3]);
}
__device__ __forceinline__ void stv4(ushort* p, float4v v){
  ushort4 o; o.x=f2b(v[0]); o.y=f2b(v[1]); o.z=f2b(v[2]); o.w=f2b(v[3]);
  *(ushort4*)p = o;
}

// merged x+Wi f32->bf16 convert (both sizes multiples of 8)
__global__ __launch_bounds__(256) void conv2_bf16_kernel(
    const float* __restrict__ a, ushort* __restrict__ oa, long na,
    const float* __restrict__ b, ushort* __restrict__ ob, long nb)
{
  long i = ((long)blockIdx.x*256 + threadIdx.x) * 8;
  if (i < na) {
    st4(oa + i, *(const float4*)(a + i));
    st4(oa + i + 4, *(const float4*)(a + i + 4));
  } else {
    long j = i - na;
    if (j < nb) {
      st4(ob + j, *(const float4*)(b + j));
      st4(ob + j + 4, *(const float4*)(b + j + 4));
    }
  }
}

__global__ __launch_bounds__(256) void f32_to_bf16_kernel(
    const float* __restrict__ in, ushort* __restrict__ out, long n)
{
  long i = ((long)blockIdx.x*256 + threadIdx.x) * 8;
  if (i >= n) return;
  st4(out + i, *(const float4*)(in + i));
  st4(out + i + 4, *(const float4*)(in + i + 4));
}

#define GLL16(g, l) __builtin_amdgcn_global_load_lds( \
    (const __attribute__((address_space(1))) void*)(g), \
    (__attribute__((address_space(3))) void*)(l), 16, 0, 0)

// ---------------------------------------------------------------------------
// MFMA bf16 NT GEMM (m97 structure, BK=64, R10/R12-verified epilogue).
// Conflict-free LDS swizzle. XCD-aware tile swizzle.
// M % 128 == 0; N guarded; K % 64 == 0.
// ---------------------------------------------------------------------------
template<typename TC>
__global__ __launch_bounds__(256) void gemm_mfma_bt(
    const ushort* __restrict__ A, int lda,
    const ushort* __restrict__ B, int ldb,
    TC* __restrict__ C, int ldc,
    int N, int K)
{
  __shared__ ushort As[2][128*32];
  __shared__ ushort Bs[2][128*32];
  const int t = threadIdx.x;
  const int lt = t & 63, w = t >> 6;
  const int wr = w >> 1, wc = w & 1;

  const int nwg = gridDim.x * gridDim.y;
  int orig = blockIdx.x + gridDim.x * blockIdx.y;
  int tile = orig;
  if ((nwg & 7) == 0) tile = (orig & 7) * (nwg >> 3) + (orig >> 3);
  const int m0 = (tile / gridDim.x) * 128;
  const int n0 = (tile % gridDim.x) * 128;

  float4v acc[4][4];
  #pragma unroll
  for (int i=0;i<4;++i)
    #pragma unroll
    for (int j=0;j<4;++j) acc[i][j] = float4v{0.f,0.f,0.f,0.f};

  const int srow = t >> 2;
  const int scol = ((t & 3) ^ ((srow >> 1) & 3)) * 8;   // source-side swizzle
  const int bn0 = min(n0 + srow, N-1);
  const int bn1 = min(n0 + 64 + srow, N-1);
  const long aoff0 = (long)(m0 + srow) * lda + scol;
  const long aoff1 = (long)(m0 + 64 + srow) * lda + scol;
  const long boff0 = (long)bn0 * ldb + scol;
  const long boff1 = (long)bn1 * ldb + scol;
  const int lr = lt & 15, lks = lt >> 4;

  for (int k0 = 0; k0 < K; k0 += 64) {
    GLL16(A + aoff0 + k0,      As[0] + t*8);
    GLL16(A + aoff1 + k0,      As[0] + 2048 + t*8);
    GLL16(B + boff0 + k0,      Bs[0] + t*8);
    GLL16(B + boff1 + k0,      Bs[0] + 2048 + t*8);
    GLL16(A + aoff0 + k0 + 32, As[1] + t*8);
    GLL16(A + aoff1 + k0 + 32, As[1] + 2048 + t*8);
    GLL16(B + boff0 + k0 + 32, Bs[1] + t*8);
    GLL16(B + boff1 + k0 + 32, Bs[1] + 2048 + t*8);
    __syncthreads();
    #pragma unroll
    for (int hB = 0; hB < 2; ++hB) {
      short8v af[4], bf[4];
      #pragma unroll
      for (int i = 0; i < 4; ++i) {
        int ra = wr*64 + i*16 + lr;
        af[i] = *(const short8v*)(As[hB] + ra*32 + ((lks ^ ((ra>>1)&3)) << 3));
        int rb = wc*64 + i*16 + lr;
        bf[i] = *(const short8v*)(Bs[hB] + rb*32 + ((lks ^ ((rb>>1)&3)) << 3));
      }
      #pragma unroll
      for (int i = 0; i < 4; ++i)
        #pragma unroll
        for (int j = 0; j < 4; ++j)
          acc[i][j] = __builtin_amdgcn_mfma_f32_16x16x32_bf16(af[i], bf[j], acc[i][j], 0, 0, 0);
    }
    __syncthreads();
  }

  const int cr = (lt >> 4) * 4;   // C/D: col=lane&15, row=(lane>>4)*4+reg (m89)
  const int cc = lt & 15;
  #pragma unroll
  for (int i = 0; i < 4; ++i) {
    #pragma unroll
    for (int j = 0; j < 4; ++j) {
      int col = n0 + wc*64 + j*16 + cc;
      if (col < N) {
        #pragma unroll
        for (int r = 0; r < 4; ++r) {
          int row = m0 + wr*64 + i*16 + cr + r;
          stc(C + (long)row*ldc + col, acc[i][j][r]);
        }
      }
    }
  }
}

// ---------------------------------------------------------------------------
// MFMA G kernel (R11/R12-verified, swapped-operand epilogue, float4 stores)
// ---------------------------------------------------------------------------
__global__ __launch_bounds__(256) void g_mfma_kernel(
    const ushort* __restrict__ conv, float* __restrict__ G)
{
  const int bc = blockIdx.x;
  const long r0 = (long)bc*CHUNK;
  __shared__ ushort Cs[128][136];
  __shared__ ushort Bs[128][136];
  const int t = threadIdx.x;
  const int lt = t & 63, w = t >> 6;
  const int lr = lt & 15, lk = (lt >> 4) * 8;

  for (int i = t; i < 128*16; i += 256) {
    int r = i >> 4, n0 = (i & 15) * 8;
    *(short8v*)&Cs[r][n0] = *(const short8v*)(conv + (r0+r)*CONVD + INTER + STATE + n0);
    *(short8v*)&Bs[r][n0] = *(const short8v*)(conv + (r0+r)*CONVD + INTER + n0);
  }
  __syncthreads();

  float4v acc[2][8];
  #pragma unroll
  for (int m=0;m<2;++m)
    #pragma unroll
    for (int j=0;j<8;++j) acc[m][j] = float4v{0,0,0,0};
  #pragma unroll
  for (int kk = 0; kk < 4; ++kk) {
    short8v a0 = *(const short8v*)&Cs[w*32 +      lr][kk*32 + lk];
    short8v a1 = *(const short8v*)&Cs[w*32 + 16 + lr][kk*32 + lk];
    #pragma unroll
    for (int nj = 0; nj < 8; ++nj) {
      short8v bv = *(const short8v*)&Bs[nj*16 + lr][kk*32 + lk];
      acc[0][nj] = __builtin_amdgcn_mfma_f32_16x16x32_bf16(bv, a0, acc[0][nj], 0, 0, 0);
      acc[1][nj] = __builtin_amdgcn_mfma_f32_16x16x32_bf16(bv, a1, acc[1][nj], 0, 0, 0);
    }
  }
  float* Gb = G + (long)bc*CHUNK*CHUNK;
  const int cl = lt & 15, cs4 = (lt >> 4) * 4;
  #pragma unroll
  for (int m = 0; m < 2; ++m) {
    int l = w*32 + m*16 + cl;
    #pragma unroll
    for (int nj = 0; nj < 8; ++nj)
      stv4(Gb + l*CHUNK + nj*16 + cs4, acc[m][nj]);
  }
}

// ---------------------------------------------------------------------------
// Depthwise causal conv (K=4) + bias + SiLU (R12-verified 4-wide)
// ---------------------------------------------------------------------------
__global__ __launch_bounds__(256) void conv_silu_kernel(
    const ushort* __restrict__ proj, const float* __restrict__ cw,
    const float* __restrict__ cb, ushort* __restrict__ out)
{
  const int C4 = CONVD/4;
  long idx = (long)blockIdx.x*256 + threadIdx.x;
  if (idx >= (long)ROWS*C4) return;
  int r = (int)(idx / C4);
  int c = (int)(idx % C4) * 4;
  int tt = r & (SEQL-1);
  float4 bv = *(const float4*)(cb + c);
  float acc0=bv.x, acc1=bv.y, acc2=bv.z, acc3=bv.w;
  float4 w0 = *(const float4*)(cw + (c+0)*KCONV);
  float4 w1 = *(const float4*)(cw + (c+1)*KCONV);
  float4 w2 = *(const float4*)(cw + (c+2)*KCONV);
  float4 w3 = *(const float4*)(cw + (c+3)*KCONV);
  const float wj0[4] = {w0.x,w0.y,w0.z,w0.w};
  const float wj1[4] = {w1.x,w1.y,w1.z,w1.w};
  const float wj2[4] = {w2.x,w2.y,w2.z,w2.w};
  const float wj3[4] = {w3.x,w3.y,w3.z,w3.w};
  #pragma unroll
  for (int j = 0; j < KCONV; ++j) {
    int tr = tt - (KCONV-1) + j;
    if (tr >= 0) {
      float4 v = ld4(proj + (long)(r - (KCONV-1) + j)*PROJD + INTER + c);
      acc0 = fmaf(v.x, wj0[j], acc0);
      acc1 = fmaf(v.y, wj1[j], acc1);
      acc2 = fmaf(v.z, wj2[j], acc2);
      acc3 = fmaf(v.w, wj3[j], acc3);
    }
  }
  float4 o;
  o.x = acc0 * sigmoidf_(acc0);
  o.y = acc1 * sigmoidf_(acc1);
  o.z = acc2 * sigmoidf_(acc2);
  o.w = acc3 * sigmoidf_(acc3);
  st4(out + (long)r*CONVD + c, o);
}

// ---------------------------------------------------------------------------
// Fused dt (softplus) + per-chunk cumsum of A*dt (R8-verified)
// ---------------------------------------------------------------------------
__global__ __launch_bounds__(256) void dt_acum_kernel(
    const ushort* __restrict__ proj, const float* __restrict__ dt_bias,
    const float* __restrict__ A_log, float* __restrict__ dtb,
    float* __restrict__ acum)
{
  const int bc = blockIdx.x;
  const long r0 = (long)bc*CHUNK;
  __shared__ float dts[CHUNK][NHEADS+1];
  const int t = threadIdx.x;
  for (int i = t; i < CHUNK*8; i += 256) {
    int l = i >> 3, h0 = (i & 7) * 8;
    short8v v = *(const short8v*)(proj + (r0+l)*PROJD + INTER + CONVD + h0);
    #pragma unroll
    for (int j = 0; j < 8; ++j) {
      float xv = b2f((ushort)v[j]) + dt_bias[h0+j];
      float sp = fmaxf(xv, 0.f) + __logf(1.f + __expf(-fabsf(xv)));
      dts[l][h0+j] = sp;
      dtb[(r0+l)*NHEADS + h0 + j] = sp;
    }
  }
  __syncthreads();
  if (t < NHEADS) {
    float Ah = -__expf(A_log[t]);
    float acc = 0.f;
    float* o = acum + ((long)bc*NHEADS + t)*CHUNK;
    for (int l = 0; l < CHUNK; ++l) { acc = fmaf(Ah, dts[l][t], acc); o[l] = acc; }
  }
}

// ---------------------------------------------------------------------------
// MFMA states kernel (R11/R12-verified, swapped-operand epilogue, 8B stores)
// ---------------------------------------------------------------------------
__global__ __launch_bounds__(256) void states_mfma_kernel(
    const ushort* __restrict__ conv, const float* __restrict__ dtb,
    const float* __restrict__ acum, ushort* __restrict__ states)
{
  const int h = blockIdx.x, c = blockIdx.y, b = blockIdx.z;
  const int bc = b*NCH + c;
  const long r0 = (long)bc*CHUNK;
  __shared__ ushort Ahi[64][136];
  __shared__ ushort Alo[64][136];
  __shared__ ushort Bt[128][136];
  __shared__ float arow[CHUNK];
  __shared__ float wrow[CHUNK];
  const int t = threadIdx.x;
  const int lt = t & 63, w = t >> 6;
  const int lr = lt & 15, lk = (lt >> 4) * 8;

  if (t < CHUNK) arow[t] = acum[((long)bc*NHEADS + h)*CHUNK + t];
  __syncthreads();
  if (t < CHUNK) wrow[t] = dtb[(r0 + t)*NHEADS + h] * __expf(arow[CHUNK-1] - arow[t]);
  __syncthreads();

  for (int i = t; i < CHUNK*HEAD_DIM/8; i += 256) {
    int l = i >> 3, p0 = (i & 7) * 8;
    short8v v = *(const short8v*)(conv + (r0+l)*CONVD + h*HEAD_DIM + p0);
    float wl = wrow[l];
    #pragma unroll
    for (int j = 0; j < 8; ++j) {
      float f = b2f((ushort)v[j]) * wl;
      ushort hb = f2b(f);
      Ahi[p0+j][l] = hb;
      Alo[p0+j][l] = f2b(f - b2f(hb));
    }
  }
  for (int i = t; i < CHUNK*STATE/8; i += 256) {
    int l = i >> 4, n0 = (i & 15) * 8;
    short8v v = *(const short8v*)(conv + (r0+l)*CONVD + INTER + n0);
    #pragma unroll
    for (int j = 0; j < 8; ++j) Bt[n0+j][l] = (ushort)v[j];
  }
  __syncthreads();

  float4v acc[8];
  #pragma unroll
  for (int j = 0; j < 8; ++j) acc[j] = float4v{0,0,0,0};
  #pragma unroll
  for (int kk = 0; kk < 4; ++kk) {
    short8v ahi = *(const short8v*)&Ahi[w*16 + lr][kk*32 + lk];
    short8v alo = *(const short8v*)&Alo[w*16 + lr][kk*32 + lk];
    #pragma unroll
    for (int nj = 0; nj < 8; ++nj) {
      short8v bv = *(const short8v*)&Bt[nj*16 + lr][kk*32 + lk];
      acc[nj] = __builtin_amdgcn_mfma_f32_16x16x32_bf16(bv, ahi, acc[nj], 0, 0, 0);
      acc[nj] = __builtin_amdgcn_mfma_f32_16x16x32_bf16(bv, alo, acc[nj], 0, 0, 0);
    }
  }
  ushort* so = states + ((long)bc*NHEADS + h)*HEAD_DIM*STATE;
  const int cp = lt & 15, cn4 = (lt >> 4) * 4;
  const int p = w*16 + cp;
  #pragma unroll
  for (int nj = 0; nj < 8; ++nj)
    stv4(so + p*STATE + nj*16 + cn4, acc[nj]);
}

// in-place inter-chunk scan (R8/R12-verified, 4-way p-split)
__global__ __launch_bounds__(256) void scan_kernel(
    ushort* __restrict__ states, const float* __restrict__ acum)
{
  const int blk = blockIdx.x;
  const int bh = blk >> 2, pq = blk & 3;
  const int b = bh >> 6, h = bh & 63;
  const int t = threadIdx.x;
  const int base = pq * 16 * STATE;
  float acc[8];
  #pragma unroll
  for (int i=0;i<8;++i) acc[i]=0.f;
  for (int c = 0; c < NCH; ++c) {
    const long bch = ((long)(b*NCH + c)*NHEADS + h);
    float lam = __expf(acum[bch*CHUNK + CHUNK-1]);
    ushort* sb = states + bch*HEAD_DIM*STATE + base;
    #pragma unroll
    for (int i = 0; i < 8; ++i) {
      float v = b2f(sb[t + i*256]);
      sb[t + i*256] = f2b(acc[i]);
      acc[i] = fmaf(acc[i], lam, v);
    }
  }
}

// ---------------------------------------------------------------------------
// MFMA y-kernel (R11/R12-verified: fused chunk-halves, swapped epilogue,
// mh=0 zero-K skip, vectorized C-staging).
// ---------------------------------------------------------------------------
__global__ __launch_bounds__(256) void y_mfma_kernel(
    const ushort* __restrict__ conv, const float* __restrict__ dtb,
    const float* __restrict__ acum, const float* __restrict__ G,
    const ushort* __restrict__ states, const float* __restrict__ Dp,
    ushort* __restrict__ proj)
{
  const int h = blockIdx.x, c = blockIdx.y, b = blockIdx.z;
  const int bc = b*NCH + c;
  const long r0 = (long)bc*CHUNK;

  __shared__ float  Af[64][132];     // W (f32), then C; per-mh
  __shared__ ushort B0[64][136];     // hid^T: B0[p][s], full chunk
  __shared__ ushort B1[64][136];     // init:  B1[p][n]
  __shared__ float arow[CHUNK];
  __shared__ float dtr[CHUNK];
  __shared__ float el[CHUNK];

  const int t = threadIdx.x;
  const int lt = t & 63, w = t >> 6;
  const int lr = lt & 15, lk = (lt >> 4) * 8;

  if (t < CHUNK) {
    arow[t] = acum[((long)bc*NHEADS + h)*CHUNK + t];
    dtr[t]  = dtb[(r0 + t)*NHEADS + h];
  }
  __syncthreads();

  if (t < CHUNK) el[t] = __expf(arow[t]);
  // B0 = hid^T (full chunk)
  for (int i = t; i < CHUNK*HEAD_DIM/8; i += 256) {
    int s = i >> 3, p0 = (i & 7) * 8;
    short8v v = *(const short8v*)(conv + (r0+s)*CONVD + h*HEAD_DIM + p0);
    #pragma unroll
    for (int j = 0; j < 8; ++j) B0[p0+j][s] = (ushort)v[j];
  }
  // B1 = init states
  {
    const ushort* stb = states + ((long)bc*NHEADS + h)*HEAD_DIM*STATE;
    for (int i = t; i < HEAD_DIM*STATE/8; i += 256) {
      int p = i >> 4, n0 = (i & 15) * 8;
      *(short8v*)&B1[p][n0] = *(const short8v*)(stb + p*STATE + n0);
    }
  }
  // Af = W(mh=0): rows 0..63, cols 0..63 only (s<=l<64)
  {
    const float* Gb = G + (long)bc*CHUNK*CHUNK;
    for (int i = t; i < 64*64; i += 256) {
      int ll = i >> 6, s = i & 63;
      float wv = 0.f;
      if (s <= ll) wv = Gb[ll*CHUNK + s] * __expf(arow[ll] - arow[s]) * dtr[s];
      Af[ll][s] = wv;
    }
  }
  __syncthreads();

  const float Dh = Dp[h];
  const int cl = lt & 15, cp4 = (lt >> 4) * 4;

  #pragma unroll
  for (int mh = 0; mh < 2; ++mh) {
    const int mbase = mh * 64;
    if (mh == 1) {
      __syncthreads();     // mm2(0) readers of Af done
      const float* Gb = G + (long)bc*CHUNK*CHUNK;
      for (int i = t; i < 64*CHUNK; i += 256) {
        int ll = i >> 7, s = i & 127;
        int l = 64 + ll;
        float wv = 0.f;
        if (s <= l) wv = Gb[l*CHUNK + s] * __expf(arow[l] - arow[s]) * dtr[s];
        Af[ll][s] = wv;
      }
      __syncthreads();
    }

    float4v acc1[4], acc2[4];
    #pragma unroll
    for (int j = 0; j < 4; ++j) { acc1[j] = float4v{0,0,0,0}; acc2[j] = float4v{0,0,0,0}; }

    // mm1: Y_diag, W split hi/lo (mh=0: only K columns 0..63 nonzero)
    const int kkmax = mh ? 4 : 2;
    for (int kk = 0; kk < kkmax; ++kk) {
      const float* ap = &Af[w*16 + lr][kk*32 + lk];
      float a8[8];
      *(float4*)&a8[0] = *(const float4*)ap;
      *(float4*)&a8[4] = *(const float4*)(ap + 4);
      short8v ahi, alo;
      #pragma unroll
      for (int e = 0; e < 8; ++e) {
        ushort hb = f2b(a8[e]);
        float rem = a8[e] - b2f(hb);
        ahi[e] = (short)hb;
        alo[e] = (short)f2b(rem);
      }
      #pragma unroll
      for (int nj = 0; nj < 4; ++nj) {
        short8v bfv = *(const short8v*)&B0[nj*16 + lr][kk*32 + lk];
        acc1[nj] = __builtin_amdgcn_mfma_f32_16x16x32_bf16(bfv, ahi, acc1[nj], 0, 0, 0);
        acc1[nj] = __builtin_amdgcn_mfma_f32_16x16x32_bf16(bfv, alo, acc1[nj], 0, 0, 0);
      }
    }
    __syncthreads();

    // Af = C rows of this half (exact bf16 values, staged f32) — vectorized
    for (int i = t; i < 64*STATE/8; i += 256) {
      int ll = i >> 4, n0 = (i & 15) * 8;
      short8v v = *(const short8v*)(conv + (r0 + mbase + ll)*CONVD + INTER + STATE + n0);
      #pragma unroll
      for (int j = 0; j < 8; ++j) Af[ll][n0+j] = b2f((ushort)v[j]);
    }
    __syncthreads();

    // mm2: C @ init^T (exact)
    #pragma unroll
    for (int kk = 0; kk < 4; ++kk) {
      const float* ap = &Af[w*16 + lr][kk*32 + lk];
      float a8[8];
      *(float4*)&a8[0] = *(const float4*)ap;
      *(float4*)&a8[4] = *(const float4*)(ap + 4);
      short8v ahi;
      #pragma unroll
      for (int e = 0; e < 8; ++e) ahi[e] = (short)f2b(a8[e]);
      #pragma unroll
      for (int nj = 0; nj < 4; ++nj) {
        short8v bfv = *(const short8v*)&B1[nj*16 + lr][kk*32 + lk];
        acc2[nj] = __builtin_amdgcn_mfma_f32_16x16x32_bf16(bfv, ahi, acc2[nj], 0, 0, 0);
      }
    }

    // epilogue: swapped mapping -> lane owns l = w*16+cl, 4 consecutive p
    const int ll = w*16 + cl;
    const float elv = el[mbase + ll];
    #pragma unroll
    for (int nj = 0; nj < 4; ++nj) {
      int p0 = nj*16 + cp4;
      float4v yv;
      #pragma unroll
      for (int r = 0; r < 4; ++r) {
        float hid_raw = b2f(B0[p0 + r][mbase + ll]);
        yv[r] = acc1[nj][r] + elv*acc2[nj][r] + Dh*hid_raw;
      }
      stv4(proj + (r0 + mbase + ll)*PROJD + INTER + h*HEAD_DIM + p0, yv);
    }
  }
}

// yg = y*silu(gate); rmsnorm — 16B loads/stores (kept from R13 batch)
__global__ __launch_bounds__(256) void gate_norm_kernel(
    ushort* __restrict__ proj, const float* __restrict__ nw)
{
  const int r = blockIdx.x;
  const int t = threadIdx.x;
  __shared__ float red[256];
  ushort* gate = proj + (long)r*PROJD;
  ushort* y = gate + INTER;
  float vals[16];
  float ss = 0.f;
  #pragma unroll
  for (int k = 0; k < 2; ++k) {
    int j = (t + k*256) * 8;
    short8v g8 = *(const short8v*)(gate + j);
    short8v y8 = *(const short8v*)(y + j);
    #pragma unroll
    for (int e = 0; e < 8; ++e) {
      float gv = b2f((ushort)g8[e]);
      float yv = b2f((ushort)y8[e]);
      float v = yv * gv * sigmoidf_(gv);
      vals[k*8+e] = v;
      ss += v*v;
    }
  }
  red[t] = ss;
  __syncthreads();
  for (int sft = 128; sft > 0; sft >>= 1) {
    if (t < sft) red[t] += red[t+sft];
    __syncthreads();
  }
  float scale = rsqrtf(red[0] / (float)INTER + EPSV);
  #pragma unroll
  for (int k = 0; k < 2; ++k) {
    int j = (t + k*256) * 8;
    short8v o;
    #pragma unroll
    for (int e = 0; e < 8; ++e)
      o[e] = (short)f2b(vals[k*8+e] * scale * nw[j+e]);
    *(short8v*)(y + j) = o;
  }
}

extern "C" void kernel_launch(void* const* d_in, const int* in_sizes, int n_in,
                              void* d_out, int out_size, void* d_ws, size_t ws_size,
                              hipStream_t stream) {
  const float* x       = (const float*)d_in[0];
  const float* Wi      = (const float*)d_in[1];
  const float* cw      = (const float*)d_in[2];
  const float* cb      = (const float*)d_in[3];
  const float* dt_bias = (const float*)d_in[4];
  const float* A_log   = (const float*)d_in[5];
  const float* Dp      = (const float*)d_in[6];
  const float* nw      = (const float*)d_in[7];
  const float* Wo      = (const float*)d_in[8];
  float* out = (float*)d_out;

  ushort* projb = (ushort*)d_ws;
  ushort* R     = projb + (size_t)ROWS*PROJD;
  ushort* xb    = R;
  ushort* Wib   = R + (size_t)ROWS*EMB;
  ushort* Wob   = R;
  ushort* convb = R;
  float*  dtb   = (float*)(convb + (size_t)ROWS*CONVD);
  float*  acum  = dtb  + (size_t)ROWS*NHEADS;
  float*  Gb    = acum + (size_t)NBATCH*NCH*NHEADS*CHUNK;
  ushort* st    = (ushort*)(Gb + (size_t)NBATCH*NCH*CHUNK*CHUNK);

  size_t need = (size_t)ROWS*PROJD*2 + (size_t)ROWS*CONVD*2
              + (size_t)ROWS*NHEADS*4 + (size_t)NBATCH*NCH*NHEADS*CHUNK*4
              + (size_t)NBATCH*NCH*CHUNK*CHUNK*4
              + (size_t)NBATCH*NCH*NHEADS*HEAD_DIM*STATE*2;
  if (ws_size < need) return;

  // 0. convert x + Wi to bf16 (single launch)
  {
    long na = (long)ROWS*EMB, nb = (long)PROJD*EMB;
    conv2_bf16_kernel<<<(int)((na+nb)/8/256), 256, 0, stream>>>(x, xb, na, Wi, Wib, nb);
  }
  // 1. proj = x @ Wi^T  (MFMA BK=64) -> bf16; grid 67x32
  gemm_mfma_bt<ushort><<<dim3((PROJD+127)/128, ROWS/128), 256, 0, stream>>>(
      xb, EMB, Wib, EMB, projb, PROJD, PROJD, EMB);
  // 2. causal depthwise conv + silu -> bf16
  conv_silu_kernel<<<(int)(((long)ROWS*(CONVD/4)+255)/256), 256, 0, stream>>>(
      projb, cw, cb, convb);
  // 3. fused dt softplus + chunk cumsum of A*dt
  dt_acum_kernel<<<NBATCH*NCH, 256, 0, stream>>>(projb, dt_bias, A_log, dtb, acum);
  // 4. G = C B^T per (b,chunk)  (MFMA)
  g_mfma_kernel<<<NBATCH*NCH, 256, 0, stream>>>(convb, Gb);
  // 5. per-chunk end states -> bf16 (MFMA)
  states_mfma_kernel<<<dim3(NHEADS, NCH, NBATCH), 256, 0, stream>>>(convb, dtb, acum, st);
  // 6. sequential inter-chunk scan (in place, 4-way p-split)
  scan_kernel<<<NBATCH*NHEADS*4, 256, 0, stream>>>(st, acum);
  // 7. y = Y_diag + Y_off + D*hid  (MFMA, both halves fused; 1024 blocks)
  y_mfma_kernel<<<dim3(NHEADS, NCH, NBATCH), 256, 0, stream>>>(
      convb, dtb, acum, Gb, st, Dp, projb);
  // 8. gating + RMSNorm (in place, bf16, 16B vec)
  gate_norm_kernel<<<ROWS, 256, 0, stream>>>(projb, nw);
  // 8.5 convert Wo to bf16
  f32_to_bf16_kernel<<<(int)((long)EMB*INTER/8/256), 256, 0, stream>>>(Wo, Wob, (long)EMB*INTER);
  // 9. out = yn @ Wo^T  (MFMA BK=64) -> f32; 16x32
  gemm_mfma_bt<float><<<dim3(EMB/128, ROWS/128), 256, 0, stream>>>(
      projb + INTER, PROJD, Wob, INTER, out, EMB, EMB, INTER);
}

// Round 15
// 551.095 us; speedup vs baseline: 1.0250x; 1.0066x over previous
//
#include <hip/hip_runtime.h>
#include <math.h>

#define NHEADS   64
#define EMB      2048
#define STATE    128
#define KCONV    4
#define HEAD_DIM 64
#define CHUNK    128
#define SEQL     2048
#define NBATCH   2
#define NCH      (SEQL/CHUNK)          // 16
#define INTER    (NHEADS*HEAD_DIM)     // 4096
#define CONVD    (INTER + 2*STATE)     // 4352
#define PROJD    (INTER + CONVD + NHEADS) // 8512
#define ROWS     (NBATCH*SEQL)         // 4096
#define EPSV     1e-6f

__device__ __forceinline__ float sigmoidf_(float x){ return 1.f/(1.f+__expf(-x)); }

__device__ __forceinline__ float b2f(ushort u){
  union{float f; unsigned u;} x; x.u = ((unsigned)u)<<16; return x.f;
}
__device__ __forceinline__ ushort f2b(float f){
  union{float f; unsigned u;} x; x.f=f;
  unsigned r = x.u + 0x7FFFu + ((x.u>>16)&1u);
  return (ushort)(r>>16);
}
__device__ __forceinline__ float4 ld4(const float* p){ return *(const float4*)p; }
__device__ __forceinline__ float4 ld4(const ushort* p){
  ushort4 v = *(const ushort4*)p;
  return make_float4(b2f(v.x),b2f(v.y),b2f(v.z),b2f(v.w));
}
__device__ __forceinline__ void st4(float* p, float4 v){ *(float4*)p = v; }
__device__ __forceinline__ void st4(ushort* p, float4 v){
  ushort4 o; o.x=f2b(v.x); o.y=f2b(v.y); o.z=f2b(v.z); o.w=f2b(v.w);
  *(ushort4*)p = o;
}
__device__ __forceinline__ void stc(float* p, float v){ *p = v; }
__device__ __forceinline__ void stc(ushort* p, float v){ *p = f2b(v); }

typedef __attribute__((ext_vector_type(8))) short short8v;   // 8 bf16 = 4 VGPR
typedef __attribute__((ext_vector_type(4))) float float4v;

// vector store of one acc frag (4 consecutive elems on the reg axis)
__device__ __forceinline__ void stv4(float* p, float4v v){
  *(float4*)p = make_float4(v[0],v[1],v[2],v[3]);
}
__device__ __forceinline__ void stv4(ushort* p, float4v v){
  ushort4 o; o.x=f2b(v[0]); o.y=f2b(v[1]); o.z=f2b(v[2]); o.w=f2b(v[3]);
  *(ushort4*)p = o;
}

// merged x+Wi f32->bf16 convert (both sizes multiples of 8)
__global__ __launch_bounds__(256) void conv2_bf16_kernel(
    const float* __restrict__ a, ushort* __restrict__ oa, long na,
    const float* __restrict__ b, ushort* __restrict__ ob, long nb)
{
  long i = ((long)blockIdx.x*256 + threadIdx.x) * 8;
  if (i < na) {
    st4(oa + i, *(const float4*)(a + i));
    st4(oa + i + 4, *(const float4*)(a + i + 4));
  } else {
    long j = i - na;
    if (j < nb) {
      st4(ob + j, *(const float4*)(b + j));
      st4(ob + j + 4, *(const float4*)(b + j + 4));
    }
  }
}

#define GLL16(g, l) __builtin_amdgcn_global_load_lds( \
    (const __attribute__((address_space(1))) void*)(g), \
    (__attribute__((address_space(3))) void*)(l), 16, 0, 0)

// ---------------------------------------------------------------------------
// MFMA bf16 NT GEMM (m97 structure, BK=64, R10/R12/R14-verified).
// Conflict-free LDS swizzle. XCD-aware tile swizzle.
// M % 128 == 0; N guarded; K % 64 == 0.
// ---------------------------------------------------------------------------
template<typename TC>
__global__ __launch_bounds__(256) void gemm_mfma_bt(
    const ushort* __restrict__ A, int lda,
    const ushort* __restrict__ B, int ldb,
    TC* __restrict__ C, int ldc,
    int N, int K)
{
  __shared__ ushort As[2][128*32];
  __shared__ ushort Bs[2][128*32];
  const int t = threadIdx.x;
  const int lt = t & 63, w = t >> 6;
  const int wr = w >> 1, wc = w & 1;

  const int nwg = gridDim.x * gridDim.y;
  int orig = blockIdx.x + gridDim.x * blockIdx.y;
  int tile = orig;
  if ((nwg & 7) == 0) tile = (orig & 7) * (nwg >> 3) + (orig >> 3);
  const int m0 = (tile / gridDim.x) * 128;
  const int n0 = (tile % gridDim.x) * 128;

  float4v acc[4][4];
  #pragma unroll
  for (int i=0;i<4;++i)
    #pragma unroll
    for (int j=0;j<4;++j) acc[i][j] = float4v{0.f,0.f,0.f,0.f};

  const int srow = t >> 2;
  const int scol = ((t & 3) ^ ((srow >> 1) & 3)) * 8;   // source-side swizzle
  const int bn0 = min(n0 + srow, N-1);
  const int bn1 = min(n0 + 64 + srow, N-1);
  const long aoff0 = (long)(m0 + srow) * lda + scol;
  const long aoff1 = (long)(m0 + 64 + srow) * lda + scol;
  const long boff0 = (long)bn0 * ldb + scol;
  const long boff1 = (long)bn1 * ldb + scol;
  const int lr = lt & 15, lks = lt >> 4;

  for (int k0 = 0; k0 < K; k0 += 64) {
    GLL16(A + aoff0 + k0,      As[0] + t*8);
    GLL16(A + aoff1 + k0,      As[0] + 2048 + t*8);
    GLL16(B + boff0 + k0,      Bs[0] + t*8);
    GLL16(B + boff1 + k0,      Bs[0] + 2048 + t*8);
    GLL16(A + aoff0 + k0 + 32, As[1] + t*8);
    GLL16(A + aoff1 + k0 + 32, As[1] + 2048 + t*8);
    GLL16(B + boff0 + k0 + 32, Bs[1] + t*8);
    GLL16(B + boff1 + k0 + 32, Bs[1] + 2048 + t*8);
    __syncthreads();
    #pragma unroll
    for (int hB = 0; hB < 2; ++hB) {
      short8v af[4], bf[4];
      #pragma unroll
      for (int i = 0; i < 4; ++i) {
        int ra = wr*64 + i*16 + lr;
        af[i] = *(const short8v*)(As[hB] + ra*32 + ((lks ^ ((ra>>1)&3)) << 3));
        int rb = wc*64 + i*16 + lr;
        bf[i] = *(const short8v*)(Bs[hB] + rb*32 + ((lks ^ ((rb>>1)&3)) << 3));
      }
      #pragma unroll
      for (int i = 0; i < 4; ++i)
        #pragma unroll
        for (int j = 0; j < 4; ++j)
          acc[i][j] = __builtin_amdgcn_mfma_f32_16x16x32_bf16(af[i], bf[j], acc[i][j], 0, 0, 0);
    }
    __syncthreads();
  }

  const int cr = (lt >> 4) * 4;   // C/D: col=lane&15, row=(lane>>4)*4+reg (m89)
  const int cc = lt & 15;
  #pragma unroll
  for (int i = 0; i < 4; ++i) {
    #pragma unroll
    for (int j = 0; j < 4; ++j) {
      int col = n0 + wc*64 + j*16 + cc;
      if (col < N) {
        #pragma unroll
        for (int r = 0; r < 4; ++r) {
          int row = m0 + wr*64 + i*16 + cr + r;
          stc(C + (long)row*ldc + col, acc[i][j][r]);
        }
      }
    }
  }
}

// ---------------------------------------------------------------------------
// FUSED dt_acum + g_mfma (one 32-block dispatch; LDS unioned via byte array).
// Phase A = R8-verified dt_acum body; Phase B = R11/R12-verified g_mfma body.
// ---------------------------------------------------------------------------
__global__ __launch_bounds__(256) void dtg_kernel(
    const ushort* __restrict__ proj, const float* __restrict__ dt_bias,
    const float* __restrict__ A_log, const ushort* __restrict__ conv,
    float* __restrict__ dtb, float* __restrict__ acum, float* __restrict__ G)
{
  const int bc = blockIdx.x;
  const long r0 = (long)bc*CHUNK;
  __shared__ char smem[2*128*136*2];             // 69632 B
  const int t = threadIdx.x;
  const int lt = t & 63, w = t >> 6;
  const int lr = lt & 15, lk = (lt >> 4) * 8;

  // ---- phase A: dt softplus + per-chunk cumsum (dts overlays smem, 33 KB)
  {
    float (*dts)[NHEADS+1] = (float(*)[NHEADS+1])smem;
    for (int i = t; i < CHUNK*8; i += 256) {
      int l = i >> 3, h0 = (i & 7) * 8;
      short8v v = *(const short8v*)(proj + (r0+l)*PROJD + INTER + CONVD + h0);
      #pragma unroll
      for (int j = 0; j < 8; ++j) {
        float xv = b2f((ushort)v[j]) + dt_bias[h0+j];
        float sp = fmaxf(xv, 0.f) + __logf(1.f + __expf(-fabsf(xv)));
        dts[l][h0+j] = sp;
        dtb[(r0+l)*NHEADS + h0 + j] = sp;
      }
    }
    __syncthreads();
    if (t < NHEADS) {
      float Ah = -__expf(A_log[t]);
      float acc = 0.f;
      float* o = acum + ((long)bc*NHEADS + t)*CHUNK;
      for (int l = 0; l < CHUNK; ++l) { acc = fmaf(Ah, dts[l][t], acc); o[l] = acc; }
    }
  }
  __syncthreads();

  // ---- phase B: G = C B^T (Cs/Bs overlay smem, 68 KB)
  {
    ushort (*Cs)[136] = (ushort(*)[136])smem;
    ushort (*Bs)[136] = (ushort(*)[136])(smem + 128*136*2);
    for (int i = t; i < 128*16; i += 256) {
      int r = i >> 4, n0 = (i & 15) * 8;
      *(short8v*)&Cs[r][n0] = *(const short8v*)(conv + (r0+r)*CONVD + INTER + STATE + n0);
      *(short8v*)&Bs[r][n0] = *(const short8v*)(conv + (r0+r)*CONVD + INTER + n0);
    }
    __syncthreads();

    float4v acc[2][8];
    #pragma unroll
    for (int m=0;m<2;++m)
      #pragma unroll
      for (int j=0;j<8;++j) acc[m][j] = float4v{0,0,0,0};
    #pragma unroll
    for (int kk = 0; kk < 4; ++kk) {
      short8v a0 = *(const short8v*)&Cs[w*32 +      lr][kk*32 + lk];
      short8v a1 = *(const short8v*)&Cs[w*32 + 16 + lr][kk*32 + lk];
      #pragma unroll
      for (int nj = 0; nj < 8; ++nj) {
        short8v bv = *(const short8v*)&Bs[nj*16 + lr][kk*32 + lk];
        acc[0][nj] = __builtin_amdgcn_mfma_f32_16x16x32_bf16(bv, a0, acc[0][nj], 0, 0, 0);
        acc[1][nj] = __builtin_amdgcn_mfma_f32_16x16x32_bf16(bv, a1, acc[1][nj], 0, 0, 0);
      }
    }
    float* Gb = G + (long)bc*CHUNK*CHUNK;
    const int cl = lt & 15, cs4 = (lt >> 4) * 4;
    #pragma unroll
    for (int m = 0; m < 2; ++m) {
      int l = w*32 + m*16 + cl;
      #pragma unroll
      for (int nj = 0; nj < 8; ++nj)
        stv4(Gb + l*CHUNK + nj*16 + cs4, acc[m][nj]);
    }
  }
}

// ---------------------------------------------------------------------------
// Depthwise causal conv (K=4) + bias + SiLU (R12-verified 4-wide)
// ---------------------------------------------------------------------------
__global__ __launch_bounds__(256) void conv_silu_kernel(
    const ushort* __restrict__ proj, const float* __restrict__ cw,
    const float* __restrict__ cb, ushort* __restrict__ out)
{
  const int C4 = CONVD/4;
  long idx = (long)blockIdx.x*256 + threadIdx.x;
  if (idx >= (long)ROWS*C4) return;
  int r = (int)(idx / C4);
  int c = (int)(idx % C4) * 4;
  int tt = r & (SEQL-1);
  float4 bv = *(const float4*)(cb + c);
  float acc0=bv.x, acc1=bv.y, acc2=bv.z, acc3=bv.w;
  float4 w0 = *(const float4*)(cw + (c+0)*KCONV);
  float4 w1 = *(const float4*)(cw + (c+1)*KCONV);
  float4 w2 = *(const float4*)(cw + (c+2)*KCONV);
  float4 w3 = *(const float4*)(cw + (c+3)*KCONV);
  const float wj0[4] = {w0.x,w0.y,w0.z,w0.w};
  const float wj1[4] = {w1.x,w1.y,w1.z,w1.w};
  const float wj2[4] = {w2.x,w2.y,w2.z,w2.w};
  const float wj3[4] = {w3.x,w3.y,w3.z,w3.w};
  #pragma unroll
  for (int j = 0; j < KCONV; ++j) {
    int tr = tt - (KCONV-1) + j;
    if (tr >= 0) {
      float4 v = ld4(proj + (long)(r - (KCONV-1) + j)*PROJD + INTER + c);
      acc0 = fmaf(v.x, wj0[j], acc0);
      acc1 = fmaf(v.y, wj1[j], acc1);
      acc2 = fmaf(v.z, wj2[j], acc2);
      acc3 = fmaf(v.w, wj3[j], acc3);
    }
  }
  float4 o;
  o.x = acc0 * sigmoidf_(acc0);
  o.y = acc1 * sigmoidf_(acc1);
  o.z = acc2 * sigmoidf_(acc2);
  o.w = acc3 * sigmoidf_(acc3);
  st4(out + (long)r*CONVD + c, o);
}

// ---------------------------------------------------------------------------
// MFMA states kernel (R11/R12-verified, swapped-operand epilogue, 8B stores)
// ---------------------------------------------------------------------------
__global__ __launch_bounds__(256) void states_mfma_kernel(
    const ushort* __restrict__ conv, const float* __restrict__ dtb,
    const float* __restrict__ acum, ushort* __restrict__ states)
{
  const int h = blockIdx.x, c = blockIdx.y, b = blockIdx.z;
  const int bc = b*NCH + c;
  const long r0 = (long)bc*CHUNK;
  __shared__ ushort Ahi[64][136];
  __shared__ ushort Alo[64][136];
  __shared__ ushort Bt[128][136];
  __shared__ float arow[CHUNK];
  __shared__ float wrow[CHUNK];
  const int t = threadIdx.x;
  const int lt = t & 63, w = t >> 6;
  const int lr = lt & 15, lk = (lt >> 4) * 8;

  if (t < CHUNK) arow[t] = acum[((long)bc*NHEADS + h)*CHUNK + t];
  __syncthreads();
  if (t < CHUNK) wrow[t] = dtb[(r0 + t)*NHEADS + h] * __expf(arow[CHUNK-1] - arow[t]);
  __syncthreads();

  for (int i = t; i < CHUNK*HEAD_DIM/8; i += 256) {
    int l = i >> 3, p0 = (i & 7) * 8;
    short8v v = *(const short8v*)(conv + (r0+l)*CONVD + h*HEAD_DIM + p0);
    float wl = wrow[l];
    #pragma unroll
    for (int j = 0; j < 8; ++j) {
      float f = b2f((ushort)v[j]) * wl;
      ushort hb = f2b(f);
      Ahi[p0+j][l] = hb;
      Alo[p0+j][l] = f2b(f - b2f(hb));
    }
  }
  for (int i = t; i < CHUNK*STATE/8; i += 256) {
    int l = i >> 4, n0 = (i & 15) * 8;
    short8v v = *(const short8v*)(conv + (r0+l)*CONVD + INTER + n0);
    #pragma unroll
    for (int j = 0; j < 8; ++j) Bt[n0+j][l] = (ushort)v[j];
  }
  __syncthreads();

  float4v acc[8];
  #pragma unroll
  for (int j = 0; j < 8; ++j) acc[j] = float4v{0,0,0,0};
  #pragma unroll
  for (int kk = 0; kk < 4; ++kk) {
    short8v ahi = *(const short8v*)&Ahi[w*16 + lr][kk*32 + lk];
    short8v alo = *(const short8v*)&Alo[w*16 + lr][kk*32 + lk];
    #pragma unroll
    for (int nj = 0; nj < 8; ++nj) {
      short8v bv = *(const short8v*)&Bt[nj*16 + lr][kk*32 + lk];
      acc[nj] = __builtin_amdgcn_mfma_f32_16x16x32_bf16(bv, ahi, acc[nj], 0, 0, 0);
      acc[nj] = __builtin_amdgcn_mfma_f32_16x16x32_bf16(bv, alo, acc[nj], 0, 0, 0);
    }
  }
  ushort* so = states + ((long)bc*NHEADS + h)*HEAD_DIM*STATE;
  const int cp = lt & 15, cn4 = (lt >> 4) * 4;
  const int p = w*16 + cp;
  #pragma unroll
  for (int nj = 0; nj < 8; ++nj)
    stv4(so + p*STATE + nj*16 + cn4, acc[nj]);
}

// in-place inter-chunk scan (R8/R12-verified, 4-way p-split)
__global__ __launch_bounds__(256) void scan_kernel(
    ushort* __restrict__ states, const float* __restrict__ acum)
{
  const int blk = blockIdx.x;
  const int bh = blk >> 2, pq = blk & 3;
  const int b = bh >> 6, h = bh & 63;
  const int t = threadIdx.x;
  const int base = pq * 16 * STATE;
  float acc[8];
  #pragma unroll
  for (int i=0;i<8;++i) acc[i]=0.f;
  for (int c = 0; c < NCH; ++c) {
    const long bch = ((long)(b*NCH + c)*NHEADS + h);
    float lam = __expf(acum[bch*CHUNK + CHUNK-1]);
    ushort* sb = states + bch*HEAD_DIM*STATE + base;
    #pragma unroll
    for (int i = 0; i < 8; ++i) {
      float v = b2f(sb[t + i*256]);
      sb[t + i*256] = f2b(acc[i]);
      acc[i] = fmaf(acc[i], lam, v);
    }
  }
}

// ---------------------------------------------------------------------------
// MFMA y-kernel (R11/R12-verified: fused chunk-halves, swapped epilogue,
// mh=0 zero-K skip, vectorized C-staging).
// ---------------------------------------------------------------------------
__global__ __launch_bounds__(256) void y_mfma_kernel(
    const ushort* __restrict__ conv, const float* __restrict__ dtb,
    const float* __restrict__ acum, const float* __restrict__ G,
    const ushort* __restrict__ states, const float* __restrict__ Dp,
    ushort* __restrict__ proj)
{
  const int h = blockIdx.x, c = blockIdx.y, b = blockIdx.z;
  const int bc = b*NCH + c;
  const long r0 = (long)bc*CHUNK;

  __shared__ float  Af[64][132];     // W (f32), then C; per-mh
  __shared__ ushort B0[64][136];     // hid^T: B0[p][s], full chunk
  __shared__ ushort B1[64][136];     // init:  B1[p][n]
  __shared__ float arow[CHUNK];
  __shared__ float dtr[CHUNK];
  __shared__ float el[CHUNK];

  const int t = threadIdx.x;
  const int lt = t & 63, w = t >> 6;
  const int lr = lt & 15, lk = (lt >> 4) * 8;

  if (t < CHUNK) {
    arow[t] = acum[((long)bc*NHEADS + h)*CHUNK + t];
    dtr[t]  = dtb[(r0 + t)*NHEADS + h];
  }
  __syncthreads();

  if (t < CHUNK) el[t] = __expf(arow[t]);
  // B0 = hid^T (full chunk)
  for (int i = t; i < CHUNK*HEAD_DIM/8; i += 256) {
    int s = i >> 3, p0 = (i & 7) * 8;
    short8v v = *(const short8v*)(conv + (r0+s)*CONVD + h*HEAD_DIM + p0);
    #pragma unroll
    for (int j = 0; j < 8; ++j) B0[p0+j][s] = (ushort)v[j];
  }
  // B1 = init states
  {
    const ushort* stb = states + ((long)bc*NHEADS + h)*HEAD_DIM*STATE;
    for (int i = t; i < HEAD_DIM*STATE/8; i += 256) {
      int p = i >> 4, n0 = (i & 15) * 8;
      *(short8v*)&B1[p][n0] = *(const short8v*)(stb + p*STATE + n0);
    }
  }
  // Af = W(mh=0): rows 0..63, cols 0..63 only (s<=l<64)
  {
    const float* Gb = G + (long)bc*CHUNK*CHUNK;
    for (int i = t; i < 64*64; i += 256) {
      int ll = i >> 6, s = i & 63;
      float wv = 0.f;
      if (s <= ll) wv = Gb[ll*CHUNK + s] * __expf(arow[ll] - arow[s]) * dtr[s];
      Af[ll][s] = wv;
    }
  }
  __syncthreads();

  const float Dh = Dp[h];
  const int cl = lt & 15, cp4 = (lt >> 4) * 4;

  #pragma unroll
  for (int mh = 0; mh < 2; ++mh) {
    const int mbase = mh * 64;
    if (mh == 1) {
      __syncthreads();     // mm2(0) readers of Af done
      const float* Gb = G + (long)bc*CHUNK*CHUNK;
      for (int i = t; i < 64*CHUNK; i += 256) {
        int ll = i >> 7, s = i & 127;
        int l = 64 + ll;
        float wv = 0.f;
        if (s <= l) wv = Gb[l*CHUNK + s] * __expf(arow[l] - arow[s]) * dtr[s];
        Af[ll][s] = wv;
      }
      __syncthreads();
    }

    float4v acc1[4], acc2[4];
    #pragma unroll
    for (int j = 0; j < 4; ++j) { acc1[j] = float4v{0,0,0,0}; acc2[j] = float4v{0,0,0,0}; }

    // mm1: Y_diag, W split hi/lo (mh=0: only K columns 0..63 nonzero)
    const int kkmax = mh ? 4 : 2;
    for (int kk = 0; kk < kkmax; ++kk) {
      const float* ap = &Af[w*16 + lr][kk*32 + lk];
      float a8[8];
      *(float4*)&a8[0] = *(const float4*)ap;
      *(float4*)&a8[4] = *(const float4*)(ap + 4);
      short8v ahi, alo;
      #pragma unroll
      for (int e = 0; e < 8; ++e) {
        ushort hb = f2b(a8[e]);
        float rem = a8[e] - b2f(hb);
        ahi[e] = (short)hb;
        alo[e] = (short)f2b(rem);
      }
      #pragma unroll
      for (int nj = 0; nj < 4; ++nj) {
        short8v bfv = *(const short8v*)&B0[nj*16 + lr][kk*32 + lk];
        acc1[nj] = __builtin_amdgcn_mfma_f32_16x16x32_bf16(bfv, ahi, acc1[nj], 0, 0, 0);
        acc1[nj] = __builtin_amdgcn_mfma_f32_16x16x32_bf16(bfv, alo, acc1[nj], 0, 0, 0);
      }
    }
    __syncthreads();

    // Af = C rows of this half (exact bf16 values, staged f32) — vectorized
    for (int i = t; i < 64*STATE/8; i += 256) {
      int ll = i >> 4, n0 = (i & 15) * 8;
      short8v v = *(const short8v*)(conv + (r0 + mbase + ll)*CONVD + INTER + STATE + n0);
      #pragma unroll
      for (int j = 0; j < 8; ++j) Af[ll][n0+j] = b2f((ushort)v[j]);
    }
    __syncthreads();

    // mm2: C @ init^T (exact)
    #pragma unroll
    for (int kk = 0; kk < 4; ++kk) {
      const float* ap = &Af[w*16 + lr][kk*32 + lk];
      float a8[8];
      *(float4*)&a8[0] = *(const float4*)ap;
      *(float4*)&a8[4] = *(const float4*)(ap + 4);
      short8v ahi;
      #pragma unroll
      for (int e = 0; e < 8; ++e) ahi[e] = (short)f2b(a8[e]);
      #pragma unroll
      for (int nj = 0; nj < 4; ++nj) {
        short8v bfv = *(const short8v*)&B1[nj*16 + lr][kk*32 + lk];
        acc2[nj] = __builtin_amdgcn_mfma_f32_16x16x32_bf16(bfv, ahi, acc2[nj], 0, 0, 0);
      }
    }

    // epilogue: swapped mapping -> lane owns l = w*16+cl, 4 consecutive p
    const int ll = w*16 + cl;
    const float elv = el[mbase + ll];
    #pragma unroll
    for (int nj = 0; nj < 4; ++nj) {
      int p0 = nj*16 + cp4;
      float4v yv;
      #pragma unroll
      for (int r = 0; r < 4; ++r) {
        float hid_raw = b2f(B0[p0 + r][mbase + ll]);
        yv[r] = acc1[nj][r] + elv*acc2[nj][r] + Dh*hid_raw;
      }
      stv4(proj + (r0 + mbase + ll)*PROJD + INTER + h*HEAD_DIM + p0, yv);
    }
  }
}

// yg = y*silu(gate); rmsnorm (16B vec) + folded Wo f32->bf16 convert
// (block r also converts Wo[r*2048 .. r*2048+2048) — safe: gate_norm runs
// after y_mfma, the last consumer of convb which Wob aliases)
__global__ __launch_bounds__(256) void gate_norm_kernel(
    ushort* __restrict__ proj, const float* __restrict__ nw,
    const float* __restrict__ Wo, ushort* __restrict__ Wob)
{
  const int r = blockIdx.x;
  const int t = threadIdx.x;
  __shared__ float red[256];
  ushort* gate = proj + (long)r*PROJD;
  ushort* y = gate + INTER;
  // independent: convert this block's 2048-elem slice of Wo
  {
    long o = (long)r*2048 + t*8;
    st4(Wob + o, *(const float4*)(Wo + o));
    st4(Wob + o + 4, *(const float4*)(Wo + o + 4));
  }
  float vals[16];
  float ss = 0.f;
  #pragma unroll
  for (int k = 0; k < 2; ++k) {
    int j = (t + k*256) * 8;
    short8v g8 = *(const short8v*)(gate + j);
    short8v y8 = *(const short8v*)(y + j);
    #pragma unroll
    for (int e = 0; e < 8; ++e) {
      float gv = b2f((ushort)g8[e]);
      float yv = b2f((ushort)y8[e]);
      float v = yv * gv * sigmoidf_(gv);
      vals[k*8+e] = v;
      ss += v*v;
    }
  }
  red[t] = ss;
  __syncthreads();
  for (int sft = 128; sft > 0; sft >>= 1) {
    if (t < sft) red[t] += red[t+sft];
    __syncthreads();
  }
  float scale = rsqrtf(red[0] / (float)INTER + EPSV);
  #pragma unroll
  for (int k = 0; k < 2; ++k) {
    int j = (t + k*256) * 8;
    short8v o;
    #pragma unroll
    for (int e = 0; e < 8; ++e)
      o[e] = (short)f2b(vals[k*8+e] * scale * nw[j+e]);
    *(short8v*)(y + j) = o;
  }
}

extern "C" void kernel_launch(void* const* d_in, const int* in_sizes, int n_in,
                              void* d_out, int out_size, void* d_ws, size_t ws_size,
                              hipStream_t stream) {
  const float* x       = (const float*)d_in[0];
  const float* Wi      = (const float*)d_in[1];
  const float* cw      = (const float*)d_in[2];
  const float* cb      = (const float*)d_in[3];
  const float* dt_bias = (const float*)d_in[4];
  const float* A_log   = (const float*)d_in[5];
  const float* Dp      = (const float*)d_in[6];
  const float* nw      = (const float*)d_in[7];
  const float* Wo      = (const float*)d_in[8];
  float* out = (float*)d_out;

  ushort* projb = (ushort*)d_ws;
  ushort* R     = projb + (size_t)ROWS*PROJD;
  ushort* xb    = R;
  ushort* Wib   = R + (size_t)ROWS*EMB;
  ushort* Wob   = R;
  ushort* convb = R;
  float*  dtb   = (float*)(convb + (size_t)ROWS*CONVD);
  float*  acum  = dtb  + (size_t)ROWS*NHEADS;
  float*  Gb    = acum + (size_t)NBATCH*NCH*NHEADS*CHUNK;
  ushort* st    = (ushort*)(Gb + (size_t)NBATCH*NCH*CHUNK*CHUNK);

  size_t need = (size_t)ROWS*PROJD*2 + (size_t)ROWS*CONVD*2
              + (size_t)ROWS*NHEADS*4 + (size_t)NBATCH*NCH*NHEADS*CHUNK*4
              + (size_t)NBATCH*NCH*CHUNK*CHUNK*4
              + (size_t)NBATCH*NCH*NHEADS*HEAD_DIM*STATE*2;
  if (ws_size < need) return;

  // 0. convert x + Wi to bf16 (single launch)
  {
    long na = (long)ROWS*EMB, nb = (long)PROJD*EMB;
    conv2_bf16_kernel<<<(int)((na+nb)/8/256), 256, 0, stream>>>(x, xb, na, Wi, Wib, nb);
  }
  // 1. proj = x @ Wi^T  (MFMA BK=64) -> bf16; grid 67x32
  gemm_mfma_bt<ushort><<<dim3((PROJD+127)/128, ROWS/128), 256, 0, stream>>>(
      xb, EMB, Wib, EMB, projb, PROJD, PROJD, EMB);
  // 2. causal depthwise conv + silu -> bf16
  conv_silu_kernel<<<(int)(((long)ROWS*(CONVD/4)+255)/256), 256, 0, stream>>>(
      projb, cw, cb, convb);
  // 3. FUSED dt softplus + cumsum + G = C B^T  (one 32-block dispatch)
  dtg_kernel<<<NBATCH*NCH, 256, 0, stream>>>(projb, dt_bias, A_log, convb, dtb, acum, Gb);
  // 4. per-chunk end states -> bf16 (MFMA)
  states_mfma_kernel<<<dim3(NHEADS, NCH, NBATCH), 256, 0, stream>>>(convb, dtb, acum, st);
  // 5. sequential inter-chunk scan (in place, 4-way p-split)
  scan_kernel<<<NBATCH*NHEADS*4, 256, 0, stream>>>(st, acum);
  // 6. y = Y_diag + Y_off + D*hid  (MFMA, both halves fused; 1024 blocks)
  y_mfma_kernel<<<dim3(NHEADS, NCH, NBATCH), 256, 0, stream>>>(
      convb, dtb, acum, Gb, st, Dp, projb);
  // 7. gating + RMSNorm + folded Wo->bf16 convert
  gate_norm_kernel<<<ROWS, 256, 0, stream>>>(projb, nw, Wo, Wob);
  // 8. out = yn @ Wo^T  (MFMA BK=64) -> f32; 16x32
  gemm_mfma_bt<float><<<dim3(EMB/128, ROWS/128), 256, 0, stream>>>(
      projb + INTER, PROJD, Wob, INTER, out, EMB, EMB, INTER);
}